// Round 12
// baseline (3882.151 us; speedup 1.0000x reference)
//
#include <hip/hip_runtime.h>

typedef long long ll;

#define TPB 256

static inline dim3 gridFor(ll n){ return dim3((unsigned)((n + TPB - 1) / TPB)); }

// ---------------- misc ----------------
__global__ void k_copy(const float* __restrict__ in, float* __restrict__ out, ll n){
  ll i = (ll)blockIdx.x*blockDim.x + threadIdx.x;
  if(i<n) out[i] = in[i];
}

// ============ register-blocked conv kernels (small-spatial stages) ============
template<int COG>
__global__ void k_conv1_t(const float* __restrict__ x, const float* __restrict__ w,
                          float* __restrict__ out, int Ci,int Co,int D,int H,int W)
{
  int HW = H*W, DHW = D*HW;
  int sp = blockIdx.x*blockDim.x + threadIdx.x;
  if(sp>=DHW) return;
  int cg = blockIdx.y, b = blockIdx.z;
  int wv = sp % W, hv = (sp/W) % H, dv = sp / HW;
  ll plane = (ll)DHW;
  const float* xb = x + ((ll)b*Ci)*plane;
  const float* wb = w + ((ll)cg*COG)*Ci*27;
  float acc[COG];
#pragma unroll
  for(int u=0;u<COG;++u) acc[u]=0.f;
  float vd[3],vh[3],vw[3]; int cd[3],ch[3],cw[3];
#pragma unroll
  for(int k=0;k<3;++k){
    int dd=dv+k-1; vd[k]=((unsigned)dd<(unsigned)D)?1.f:0.f; cd[k]=min(max(dd,0),D-1);
    int hh=hv+k-1; vh[k]=((unsigned)hh<(unsigned)H)?1.f:0.f; ch[k]=min(max(hh,0),H-1);
    int ww=wv+k-1; vw[k]=((unsigned)ww<(unsigned)W)?1.f:0.f; cw[k]=min(max(ww,0),W-1);
  }
  for(int ci=0;ci<Ci;++ci){
    const float* xc = xb + (ll)ci*plane;
    float xv[27];
#pragma unroll
    for(int kd=0;kd<3;++kd)
#pragma unroll
      for(int kh=0;kh<3;++kh){
        const float* rowp = xc + ((ll)cd[kd]*H + ch[kh])*W;
        float vdh = vd[kd]*vh[kh];
#pragma unroll
        for(int kw=0;kw<3;++kw)
          xv[(kd*3+kh)*3+kw] = rowp[cw[kw]]*(vdh*vw[kw]);
      }
    const float* wc = wb + ci*27;
#pragma unroll
    for(int u=0;u<COG;++u){
      const float* wu = wc + (ll)u*Ci*27;
      float a = acc[u];
#pragma unroll
      for(int kk=0;kk<27;++kk) a += xv[kk]*wu[kk];
      acc[u]=a;
    }
  }
#pragma unroll
  for(int u=0;u<COG;++u)
    out[((ll)b*Co + cg*COG+u)*plane + sp] = fmaxf(acc[u],0.f);
}

template<int COG>
__global__ void k_conv2res_t(const float* __restrict__ cin, const float* __restrict__ xin,
                             const float* __restrict__ w2, const float* __restrict__ wsk,
                             float* __restrict__ out, int Cm,int Co,int Cs,int D,int H,int W)
{
  int HW = H*W, DHW = D*HW;
  int sp = blockIdx.x*blockDim.x + threadIdx.x;
  if(sp>=DHW) return;
  int cg = blockIdx.y, b = blockIdx.z;
  int wv = sp % W, hv = (sp/W) % H, dv = sp / HW;
  ll plane = (ll)DHW;
  float acc[COG];
  if(wsk){
    const float* xs = xin + ((ll)b*Cs)*plane + sp;
    const float* wr = wsk + (ll)cg*COG*Cs;
#pragma unroll
    for(int u=0;u<COG;++u) acc[u]=0.f;
    for(int cs=0;cs<Cs;++cs){
      float xv = xs[(ll)cs*plane];
#pragma unroll
      for(int u=0;u<COG;++u) acc[u] += xv*wr[(ll)u*Cs+cs];
    }
  } else {
#pragma unroll
    for(int u=0;u<COG;++u) acc[u] = xin[((ll)b*Co + cg*COG+u)*plane + sp];
  }
  float vd[3],vh[3],vw[3]; int cd[3],ch[3],cw[3];
#pragma unroll
  for(int k=0;k<3;++k){
    int dd=dv+k-1; vd[k]=((unsigned)dd<(unsigned)D)?1.f:0.f; cd[k]=min(max(dd,0),D-1);
    int hh=hv+k-1; vh[k]=((unsigned)hh<(unsigned)H)?1.f:0.f; ch[k]=min(max(hh,0),H-1);
    int ww=wv+k-1; vw[k]=((unsigned)ww<(unsigned)W)?1.f:0.f; cw[k]=min(max(ww,0),W-1);
  }
  const float* cb = cin + ((ll)b*Cm)*plane;
  const float* wb = w2 + ((ll)cg*COG)*Cm*27;
  for(int ci=0;ci<Cm;++ci){
    const float* xc = cb + (ll)ci*plane;
    float xv[27];
#pragma unroll
    for(int kd=0;kd<3;++kd)
#pragma unroll
      for(int kh=0;kh<3;++kh){
        const float* rowp = xc + ((ll)cd[kd]*H + ch[kh])*W;
        float vdh = vd[kd]*vh[kh];
#pragma unroll
        for(int kw=0;kw<3;++kw)
          xv[(kd*3+kh)*3+kw] = rowp[cw[kw]]*(vdh*vw[kw]);
      }
    const float* wc = wb + ci*27;
#pragma unroll
    for(int u=0;u<COG;++u){
      const float* wu = wc + (ll)u*Cm*27;
      float a = acc[u];
#pragma unroll
      for(int kk=0;kk<27;++kk) a += xv[kk]*wu[kk];
      acc[u]=a;
    }
  }
#pragma unroll
  for(int u=0;u<COG;++u)
    out[((ll)b*Co + cg*COG+u)*plane + sp] = fmaxf(acc[u],0.f);
}

// ============ LDS-tiled conv kernels (large-spatial, H,W%16==0) ============
// 16x16 outputs at fixed (b,d); per-ci 3x18-row tile, row stride 24 (2-way banks only).
#define C1_RS 24
template<int COG>
__global__ void k_conv1_lds(const float* __restrict__ x, const float* __restrict__ w,
                            float* __restrict__ out, int Ci,int Co,int D,int H,int W)
{
  const int TO = 16;
  int tilesX = W/TO, tilesY = H/TO;
  int tx = threadIdx.x & 15, ty = threadIdx.x >> 4;
  int bx = blockIdx.x;
  int tX = bx % tilesX; int tmp = bx / tilesX;
  int tY = tmp % tilesY; int dv = tmp / tilesY;
  int cg = blockIdx.y, b = blockIdx.z;
  int oh = tY*TO + ty, ow = tX*TO + tx;
  ll plane = (ll)D*H*W;
  int hbase = tY*TO - 1, wbase = tX*TO - 1;
  __shared__ float lds[3*18*C1_RS];
  float acc[COG];
#pragma unroll
  for(int u=0;u<COG;++u) acc[u]=0.f;
  const float* xb = x + ((ll)b*Ci)*plane;
  const float* wb = w + ((ll)cg*COG)*Ci*27;
  for(int ci=0;ci<Ci;++ci){
    const float* xc = xb + (ll)ci*plane;
    for(int idx=threadIdx.x; idx<3*18*18; idx+=TPB){
      int kd = idx / 324; int rem = idx - kd*324;
      int r = rem / 18, c2 = rem - r*18;
      int dd = dv + kd - 1, hh = hbase + r, ww = wbase + c2;
      float v = 0.f;
      if((unsigned)dd<(unsigned)D && (unsigned)hh<(unsigned)H && (unsigned)ww<(unsigned)W)
        v = xc[((ll)dd*H + hh)*W + ww];
      lds[(kd*18 + r)*C1_RS + c2] = v;
    }
    __syncthreads();
    float xv[27];
#pragma unroll
    for(int kd=0;kd<3;++kd)
#pragma unroll
      for(int kh=0;kh<3;++kh)
#pragma unroll
        for(int kw=0;kw<3;++kw)
          xv[(kd*3+kh)*3+kw] = lds[(kd*18 + (ty+kh))*C1_RS + (tx+kw)];
    const float* wc = wb + ci*27;
#pragma unroll
    for(int u=0;u<COG;++u){
      const float* wu = wc + (ll)u*Ci*27;
      float a = acc[u];
#pragma unroll
      for(int kk=0;kk<27;++kk) a += xv[kk]*wu[kk];
      acc[u]=a;
    }
    __syncthreads();
  }
  ll sp = ((ll)dv*H + oh)*W + ow;
#pragma unroll
  for(int u=0;u<COG;++u)
    out[((ll)b*Co + cg*COG+u)*plane + sp] = fmaxf(acc[u],0.f);
}

template<int COG>
__global__ void k_conv2res_lds(const float* __restrict__ cin, const float* __restrict__ xin,
                               const float* __restrict__ w2, const float* __restrict__ wsk,
                               float* __restrict__ out, int Cm,int Co,int Cs,int D,int H,int W)
{
  const int TO = 16;
  int tilesX = W/TO, tilesY = H/TO;
  int tx = threadIdx.x & 15, ty = threadIdx.x >> 4;
  int bx = blockIdx.x;
  int tX = bx % tilesX; int tmp = bx / tilesX;
  int tY = tmp % tilesY; int dv = tmp / tilesY;
  int cg = blockIdx.y, b = blockIdx.z;
  int oh = tY*TO + ty, ow = tX*TO + tx;
  ll plane = (ll)D*H*W;
  int hbase = tY*TO - 1, wbase = tX*TO - 1;
  __shared__ float lds[3*18*C1_RS];
  ll sp = ((ll)dv*H + oh)*W + ow;
  float acc[COG];
  {
    const float* xs = xin + ((ll)b*Cs)*plane + sp;
    const float* wr = wsk + (ll)cg*COG*Cs;
#pragma unroll
    for(int u=0;u<COG;++u) acc[u]=0.f;
    for(int cs=0;cs<Cs;++cs){
      float xv = xs[(ll)cs*plane];
#pragma unroll
      for(int u=0;u<COG;++u) acc[u] += xv*wr[(ll)u*Cs+cs];
    }
  }
  const float* cb = cin + ((ll)b*Cm)*plane;
  const float* wb = w2 + ((ll)cg*COG)*Cm*27;
  for(int ci=0;ci<Cm;++ci){
    const float* xc = cb + (ll)ci*plane;
    for(int idx=threadIdx.x; idx<3*18*18; idx+=TPB){
      int kd = idx / 324; int rem = idx - kd*324;
      int r = rem / 18, c2 = rem - r*18;
      int dd = dv + kd - 1, hh = hbase + r, ww = wbase + c2;
      float v = 0.f;
      if((unsigned)dd<(unsigned)D && (unsigned)hh<(unsigned)H && (unsigned)ww<(unsigned)W)
        v = xc[((ll)dd*H + hh)*W + ww];
      lds[(kd*18 + r)*C1_RS + c2] = v;
    }
    __syncthreads();
    float xv[27];
#pragma unroll
    for(int kd=0;kd<3;++kd)
#pragma unroll
      for(int kh=0;kh<3;++kh)
#pragma unroll
        for(int kw=0;kw<3;++kw)
          xv[(kd*3+kh)*3+kw] = lds[(kd*18 + (ty+kh))*C1_RS + (tx+kw)];
    const float* wc = wb + ci*27;
#pragma unroll
    for(int u=0;u<COG;++u){
      const float* wu = wc + (ll)u*Cm*27;
      float a = acc[u];
#pragma unroll
      for(int kk=0;kk<27;++kk) a += xv[kk]*wu[kk];
      acc[u]=a;
    }
    __syncthreads();
  }
#pragma unroll
  for(int u=0;u<COG;++u)
    out[((ll)b*Co + cg*COG+u)*plane + sp] = fmaxf(acc[u],0.f);
}

// ============ LDS-tiled conv2 + skip + relu + maxpool(1,2,2) (stages 1,2) ============
// 34-col tile stored column-permuted (even c -> c/2, odd c -> 17+c/2), row stride 36
// => the 4 j-taps are stride-1-in-tx reads (2-way banks only).
#define CP_RS 36
template<int COG>
__global__ void k_conv2respool_lds(const float* __restrict__ cin, const float* __restrict__ xin,
                                   const float* __restrict__ w2, const float* __restrict__ wsk,
                                   float* __restrict__ out, int Cm,int Co,int Cs,int D,int H,int W)
{
  const int TO = 16;
  int Ho=H/2, Wo=W/2;
  int tilesX = Wo/TO, tilesY = Ho/TO;
  int tx = threadIdx.x & 15, ty = threadIdx.x >> 4;
  int bx = blockIdx.x;
  int tX = bx % tilesX; int tmp = bx / tilesX;
  int tY = tmp % tilesY; int dv = tmp / tilesY;
  int cg = blockIdx.y, b = blockIdx.z;
  int oh = tY*TO + ty, ow = tX*TO + tx;
  ll plane = (ll)D*H*W;
  int hbase = tY*2*TO - 1, wbase = tX*2*TO - 1;
  __shared__ float lds[3*34*CP_RS];

  float acc[COG][4];
#pragma unroll
  for(int u=0;u<COG;++u){
#pragma unroll
    for(int p=0;p<4;++p) acc[u][p]=0.f;
  }
  {
    int hv=2*oh, wv=2*ow;
    ll p00 = ((ll)dv*H + hv)*W + wv;
    const float* xb = xin + ((ll)b*Cs)*plane;
    const float* wr = wsk + (ll)cg*COG*Cs;
    for(int cs=0;cs<Cs;++cs){
      const float* xc = xb + (ll)cs*plane;
      float s00=xc[p00], s01=xc[p00+1], s10=xc[p00+W], s11=xc[p00+W+1];
#pragma unroll
      for(int u=0;u<COG;++u){
        float wv_ = wr[(ll)u*Cs+cs];
        acc[u][0]+=s00*wv_; acc[u][1]+=s01*wv_; acc[u][2]+=s10*wv_; acc[u][3]+=s11*wv_;
      }
    }
  }
  const float* cb = cin + ((ll)b*Cm)*plane;
  const float* wb = w2 + ((ll)cg*COG)*Cm*27;
  for(int ci=0;ci<Cm;++ci){
    const float* xc = cb + (ll)ci*plane;
    for(int idx=threadIdx.x; idx<3*34*34; idx+=TPB){
      int kd = idx / 1156; int rem = idx - kd*1156;
      int r = rem / 34, c2 = rem - r*34;
      int dd = dv + kd - 1, hh = hbase + r, ww = wbase + c2;
      float v = 0.f;
      if((unsigned)dd<(unsigned)D && (unsigned)hh<(unsigned)H && (unsigned)ww<(unsigned)W)
        v = xc[((ll)dd*H + hh)*W + ww];
      int pc = (c2 & 1) ? (17 + (c2>>1)) : (c2>>1);
      lds[(kd*34 + r)*CP_RS + pc] = v;
    }
    __syncthreads();
    float xv[3][4][4];
#pragma unroll
    for(int kd=0;kd<3;++kd)
#pragma unroll
      for(int r=0;r<4;++r){
        int base = (kd*34 + (2*ty+r))*CP_RS;
        xv[kd][r][0] = lds[base + tx];
        xv[kd][r][1] = lds[base + 17 + tx];
        xv[kd][r][2] = lds[base + tx + 1];
        xv[kd][r][3] = lds[base + 18 + tx];
      }
    const float* wc = wb + ci*27;
#pragma unroll
    for(int u=0;u<COG;++u){
      const float* wu = wc + (ll)u*Cm*27;
#pragma unroll
      for(int py=0;py<2;++py)
#pragma unroll
        for(int px=0;px<2;++px){
          float a = acc[u][py*2+px];
#pragma unroll
          for(int kd=0;kd<3;++kd)
#pragma unroll
            for(int kh=0;kh<3;++kh)
#pragma unroll
              for(int kw=0;kw<3;++kw)
                a += xv[kd][py+kh][px+kw]*wu[(kd*3+kh)*3+kw];
          acc[u][py*2+px]=a;
        }
    }
    __syncthreads();
  }
#pragma unroll
  for(int u=0;u<COG;++u){
    float mm = fmaxf(fmaxf(acc[u][0],acc[u][1]),fmaxf(acc[u][2],acc[u][3]));
    out[(((ll)b*Co + cg*COG+u)*D + dv)*(Ho*Wo) + oh*Wo + ow] = fmaxf(mm,0.f);
  }
}

// ---------------- maxpool3d ----------------
__global__ void k_maxpool(const float* __restrict__ x, float* __restrict__ out,
                          int B,int C,int D,int H,int W,int pd,int ph,int pw)
{
  int Do = D/pd, Ho = H/ph, Wo = W/pw;
  ll total = (ll)B*C*Do*Ho*Wo;
  ll i = (ll)blockIdx.x*blockDim.x + threadIdx.x;
  if(i>=total) return;
  int w0 = (int)(i % Wo); ll t = i / Wo;
  int h0 = (int)(t % Ho); t /= Ho;
  int d0 = (int)(t % Do); t /= Do;
  int c  = (int)(t % C);  int b = (int)(t / C);
  const float* xb = x + ((ll)b*C + c)*D*H*W;
  float m = -3.4e38f;
  for(int dd=0; dd<pd; ++dd)
    for(int hh=0; hh<ph; ++hh)
      for(int ww=0; ww<pw; ++ww){
        float v = xb[(((ll)(d0*pd+dd))*H + (h0*ph+hh))*W + (w0*pw+ww)];
        m = fmaxf(m, v);
      }
  out[i] = m;
}

// ---------------- mu linear ----------------
__global__ void k_linear_red(const float* __restrict__ x, const float* __restrict__ w,
                             const float* __restrict__ bias, float* __restrict__ out,
                             int In, int Out)
{
  int o = blockIdx.x % Out;
  int b = blockIdx.x / Out;
  const float* xr = x + (ll)b*In;
  const float* wr = w + (ll)o*In;
  float s = 0.f;
  for(int i = threadIdx.x; i < In; i += blockDim.x) s += xr[i]*wr[i];
  __shared__ float red[TPB];
  red[threadIdx.x] = s; __syncthreads();
  for(int off = TPB/2; off > 0; off >>= 1){
    if(threadIdx.x < off) red[threadIdx.x] += red[threadIdx.x + off];
    __syncthreads();
  }
  if(threadIdx.x == 0) out[blockIdx.x] = red[0] + bias[o];
}

// ---------------- latent->decoder linear + relu ----------------
__global__ void k_ld(const float* __restrict__ z, const float* __restrict__ w,
                     const float* __restrict__ bias, float* __restrict__ out,
                     int B,int Out,int L)
{
  ll i = (ll)blockIdx.x*blockDim.x + threadIdx.x;
  if(i >= (ll)B*Out) return;
  int o = (int)(i % Out); int b = (int)(i / Out);
  const float* zr = z + (ll)b*L;
  const float* wr = w + (ll)o*L;
  float s = bias[o];
  for(int l=0; l<L; ++l) s += zr[l]*wr[l];
  out[i] = fmaxf(s, 0.f);
}

// ================= CSR build =================
__global__ void k_zero2(float* __restrict__ deg, int* __restrict__ cnt, int N){
  int i = blockIdx.x*blockDim.x + threadIdx.x;
  if(i<N){ deg[i]=0.f; cnt[i]=0; }
}
__global__ void k_degcnt(const int* __restrict__ row, const int* __restrict__ col,
                         float* __restrict__ deg, int* __restrict__ cnt, int E){
  int e = blockIdx.x*blockDim.x + threadIdx.x;
  if(e>=E) return;
  atomicAdd(&deg[row[e]], 1.f);
  atomicAdd(&cnt[col[e]], 1);
}
__global__ void k_scan(const int* __restrict__ cnt, int* __restrict__ rowptr,
                       int* __restrict__ cursor, int N)
{
  __shared__ int ps[TPB];
  int t = threadIdx.x;
  int chunk = (N + TPB - 1)/TPB;
  int s0 = t*chunk, s1 = min(s0+chunk, N);
  int sum = 0;
  for(int i=s0;i<s1;++i) sum += cnt[i];
  ps[t] = sum; __syncthreads();
  for(int off=1; off<TPB; off<<=1){
    int v = (t>=off)? ps[t-off] : 0; __syncthreads();
    ps[t] += v; __syncthreads();
  }
  int base = (t==0)? 0 : ps[t-1];
  for(int i=s0;i<s1;++i){ rowptr[i]=base; cursor[i]=base; base += cnt[i]; }
  if(s1==N) rowptr[N]=base;
}
__global__ void k_fill(const int* __restrict__ row, const int* __restrict__ col,
                       const float* __restrict__ deg, int* __restrict__ cursor,
                       int* __restrict__ src, float* __restrict__ wgt, int E)
{
  int e = blockIdx.x*blockDim.x + threadIdx.x;
  if(e>=E) return;
  int r = row[e], c = col[e];
  float dr = deg[r], dc = deg[c];
  float ir = dr > 0.f ? rsqrtf(dr) : 0.f;
  float ic = dc > 0.f ? rsqrtf(dc) : 0.f;
  int pos = atomicAdd(&cursor[c], 1);
  src[pos] = r;
  wgt[pos] = -(ir*ic);
}

// ================= fused Chebyshev hop =================
template<int G>
__global__ void k_cheb_hop(const float* __restrict__ v, const float* __restrict__ t0,
                           const int* __restrict__ rowptr, const int* __restrict__ src,
                           const float* __restrict__ cw, const float* __restrict__ Wk,
                           float* __restrict__ t2, float* __restrict__ xout,
                           int B,int N,int Ci,int Co,int mode)
{
  extern __shared__ float lds[]; // G*Ci
  ll g0 = (ll)blockIdx.x*G;
  ll BN = (ll)B*N;
  int tot = G*Ci;
  for(int idx=threadIdx.x; idx<tot; idx+=blockDim.x){
    int g = idx / Ci, c = idx - g*Ci;
    ll bj = g0 + g;
    float s = 0.f;
    if(bj < BN){
      if(mode==0){
        s = v[bj*(ll)Ci + c];
      } else {
        int b = (int)(bj / N), j = (int)(bj - (ll)b*N);
        int e0 = rowptr[j], e1 = rowptr[j+1];
        const float* vb = v + (ll)b*N*Ci;
        for(int e=e0;e<e1;++e) s += vb[(ll)src[e]*Ci + c]*cw[e];
        if(mode==2) s = 2.f*s - t0[bj*(ll)Ci + c];
        t2[bj*(ll)Ci + c] = s;
      }
    }
    lds[idx] = s;
  }
  __syncthreads();
  int totB = G*Co;
  for(int idx=threadIdx.x; idx<totB; idx+=blockDim.x){
    int g = idx / Co, co = idx - g*Co;
    ll bj = g0 + g;
    if(bj >= BN) continue;
    const float* tr = lds + g*Ci;
    float s = 0.f;
    for(int c=0;c<Ci;++c) s += tr[c]*Wk[(ll)c*Co + co];
    if(mode==0) xout[bj*(ll)Co+co] = s;
    else xout[bj*(ll)Co+co] += s;
  }
}

__global__ void k_inorm(float* __restrict__ x, const float* __restrict__ bias, ll BN, int C)
{
  ll r = (ll)blockIdx.x*blockDim.x + threadIdx.x;
  if(r>=BN) return;
  float* xr = x + r*(ll)C;
  float mu = 0.f;
  for(int c=0;c<C;++c){ float v = xr[c] + bias[c]; xr[c]=v; mu += v; }
  mu /= (float)C;
  float var = 0.f;
  for(int c=0;c<C;++c){ float d = xr[c]-mu; var += d*d; }
  var /= (float)C;
  float inv = rsqrtf(var + 1e-5f);
  for(int c=0;c<C;++c) xr[c] = fmaxf((xr[c]-mu)*inv, 0.f);
}

// ---------------- IGSC ----------------
__global__ void k_copycols(const float* __restrict__ x, float* __restrict__ cat,
                           ll BN, int Cx, int Ctot)
{
  ll i = (ll)blockIdx.x*blockDim.x + threadIdx.x;
  if(i >= BN*(ll)Cx) return;
  int c = (int)(i % Cx); ll r = i / Cx;
  cat[r*(ll)Ctot + c] = x[i];
}
__global__ void k_pos(const float* __restrict__ x, const float* __restrict__ igw,
                      float* __restrict__ cat, float* __restrict__ ds,
                      ll BN, int Cx, int Ctot, int posoff)
{
  ll i = (ll)blockIdx.x*blockDim.x + threadIdx.x;
  if(i>=BN) return;
  const float* xr = x + i*(ll)Cx;
  float p0=0.f,p1=0.f,p2=0.f;
  for(int c=0;c<Cx;++c){
    float v = xr[c];
    p0 += v*igw[c*3+0];
    p1 += v*igw[c*3+1];
    p2 += v*igw[c*3+2];
  }
  float* rowp = cat + i*(ll)Ctot + posoff;
  rowp[0]=p0; rowp[1]=p1; rowp[2]=p2;
  ds[i*3+0]=p0; ds[i*3+1]=p1; ds[i*3+2]=p2;
}
__global__ void k_gsample(const float* __restrict__ feat, float* __restrict__ cat,
                          int B,int N,int Cf,int D,int H,int W,int Ctot,int xoff,int posoff)
{
  ll i = (ll)blockIdx.x*blockDim.x + threadIdx.x;
  ll total = (ll)B*N*Cf;
  if(i>=total) return;
  int c = (int)(i % Cf); ll t = i / Cf;
  int n = (int)(t % N); int b = (int)(t / N);
  float* rowp = cat + ((ll)b*N + n)*Ctot;
  float px = rowp[posoff+0], py = rowp[posoff+1], pz = rowp[posoff+2];
  float gx = (2.f*px - 1.f + 1.f)*0.5f*(W-1);
  float gy = (2.f*py - 1.f + 1.f)*0.5f*(H-1);
  float gz = (2.f*pz - 1.f + 1.f)*0.5f*(D-1);
  float x0 = floorf(gx), y0 = floorf(gy), z0 = floorf(gz);
  const float* fb = feat + ((ll)b*Cf + c)*D*H*W;
  float acc = 0.f;
  for(int dz=0; dz<2; ++dz)
    for(int dy=0; dy<2; ++dy)
      for(int dx=0; dx<2; ++dx){
        float xi = x0+dx, yi = y0+dy, zi = z0+dz;
        float wgt = (1.f-fabsf(gx-xi))*(1.f-fabsf(gy-yi))*(1.f-fabsf(gz-zi));
        bool valid = (xi>=0.f)&&(xi<=(float)(W-1))&&(yi>=0.f)&&(yi<=(float)(H-1))&&(zi>=0.f)&&(zi<=(float)(D-1));
        int xc = min(max((int)xi,0),W-1);
        int yc = min(max((int)yi,0),H-1);
        int zc = min(max((int)zi,0),D-1);
        if(valid) acc += fb[((ll)zc*H + yc)*W + xc]*wgt;
      }
  rowp[xoff + c] = acc;
}

// ---------------- unpool ----------------
__global__ void k_unpool(const float* __restrict__ xin, const int* __restrict__ idx,
                         const float* __restrict__ w, float* __restrict__ out,
                         int B,int Ni,int No,int C)
{
  ll i = (ll)blockIdx.x*blockDim.x + threadIdx.x;
  ll total = (ll)B*No*C;
  if(i>=total) return;
  int c = (int)(i % C); ll t = i / C;
  int no = (int)(t % No); int b = (int)(t / No);
  float s = 0.f;
  for(int k=0;k<3;++k){
    s += xin[((ll)b*Ni + idx[no*3+k])*C + c]*w[no*3+k];
  }
  out[i] = s;
}

// ================= workspace layout (BYTE offsets, total ~126 MiB) =================
static const ll BO_A   = 0;            // f32 scratch; decoder arena
static const ll BO_B   = 75497472;
static const ll BO_C   = 94371840;
static const ll BO_L3  = 103809024;
static const ll BO_L4  = 122683392;
static const ll BO_L5  = 127401984;
static const ll BO_L6  = 129761280;
static const ll BO_P5  = 130940928;
static const ll BO_Z   = 132120576;
// decoder regions inside arena A
static const ll BO_DX   = 0;
static const ll BO_DT1  = 11792000;
static const ll BO_DT2  = 23584000;
static const ll BO_DO   = 35376000;
static const ll BO_DCAT = 41008000;
static const ll BO_DDEG = 46904000;    // float[11000]
static const ll BO_CNT  = 46948096;    // int[11008]
static const ll BO_RP   = 46992128;    // int[11008]
static const ll BO_CUR  = 47036160;    // int[11008]
static const ll BO_SRC  = 47080192;    // int[66000]
static const ll BO_CW   = 47344256;    // float[66000]

extern "C" void kernel_launch(void* const* d_in, const int* in_sizes, int n_in,
                              void* d_out, int out_size, void* d_ws, size_t ws_size,
                              hipStream_t stream)
{
  (void)in_sizes; (void)n_in; (void)out_size; (void)ws_size;
  const int B = 4;
  const float* sax = (const float*)d_in[0];
  const float *w1[7], *w2[7], *wsk[7];
  for(int i=1;i<=5;++i){
    w1[i]  = (const float*)d_in[1 + (i-1)*3];
    w2[i]  = (const float*)d_in[2 + (i-1)*3];
    wsk[i] = (const float*)d_in[3 + (i-1)*3];
  }
  w1[6] = (const float*)d_in[16]; w2[6] = (const float*)d_in[17]; wsk[6] = nullptr;
  const float* mu_w = (const float*)d_in[18];
  const float* mu_b = (const float*)d_in[19];
  const float* ld_w = (const float*)d_in[22];
  const float* ld_b = (const float*)d_in[23];
  const float *gcw[5], *gcb[5];
  for(int i=0;i<5;++i){ gcw[i] = (const float*)d_in[24+2*i]; gcb[i] = (const float*)d_in[25+2*i]; }
  const float* gcout_w = (const float*)d_in[34];
  const float* igw[4];
  for(int i=0;i<4;++i) igw[i] = (const float*)d_in[35+i];
  const int* edge[5];
  for(int i=0;i<5;++i) edge[i] = (const int*)d_in[39+i];
  const int* upidx[4]; const float* upw[4];
  for(int i=0;i<4;++i){ upidx[i] = (const int*)d_in[44+2*i]; upw[i] = (const float*)d_in[45+2*i]; }
  float* out = (float*)d_out;
  char* base = (char*)d_ws;

  float* A  = (float*)(base + BO_A);
  float* Bb = (float*)(base + BO_B);
  float* Cb = (float*)(base + BO_C);
  float* L3 = (float*)(base + BO_L3);
  float* L4 = (float*)(base + BO_L4);
  float* L5 = (float*)(base + BO_L5);
  float* L6 = (float*)(base + BO_L6);
  float* P5 = (float*)(base + BO_P5);
  float* Z  = (float*)(base + BO_Z);
  float* DX  = (float*)(base + BO_DX);
  float* DT1 = (float*)(base + BO_DT1);
  float* DT2 = (float*)(base + BO_DT2);
  float* DO_ = (float*)(base + BO_DO);
  float* DCAT= (float*)(base + BO_DCAT);
  float* DDEG= (float*)(base + BO_DDEG);
  int*   CNT = (int*)(base + BO_CNT);
  int*   RP  = (int*)(base + BO_RP);
  int*   CUR = (int*)(base + BO_CUR);
  int*   SRC = (int*)(base + BO_SRC);
  float* CW  = (float*)(base + BO_CW);

  // ============ Encoder ============
  auto convgrid = [&](int DHW, int Co, int COG){ return dim3((unsigned)((DHW+TPB-1)/TPB), Co/COG, B); };
  auto tilegrid = [&](int D,int H,int W,int Co,int COG){
    return dim3((unsigned)((H/16)*(W/16)*D), Co/COG, B);
  };

  // stage 1: 1->8 @ 16x192x192 -> Bb [4,8,16,96,96]
  k_conv1_lds<8><<<tilegrid(16,192,192,8,8),TPB,0,stream>>>(sax, w1[1], A, 1,8,16,192,192);
  k_conv2respool_lds<8><<<tilegrid(16,96,96,8,8),TPB,0,stream>>>(A, sax, w2[1], wsk[1], Bb, 8,8,1,16,192,192);
  // stage 2: 8->16 @ 16x96x96 -> Cb [4,16,16,48,48]  (conv1 COG=16: single channel-group)
  k_conv1_lds<16><<<tilegrid(16,96,96,16,16),TPB,0,stream>>>(Bb, w1[2], A, 8,16,16,96,96);
  k_conv2respool_lds<8><<<tilegrid(16,48,48,16,8),TPB,0,stream>>>(A, Bb, w2[2], wsk[2], Cb, 16,16,8,16,96,96);
  // stage 3: 16->32 @ 16x48x48 -> L3; pool(2,2,2) -> Bb  (COG=16: halve input re-staging)
  k_conv1_lds<16><<<tilegrid(16,48,48,32,16),TPB,0,stream>>>(Cb, w1[3], A, 16,32,16,48,48);
  k_conv2res_lds<16><<<tilegrid(16,48,48,32,16),TPB,0,stream>>>(A, Cb, w2[3], wsk[3], L3, 32,32,16,16,48,48);
  { ll np=(ll)B*32*8*24*24;
    k_maxpool<<<gridFor(np),TPB,0,stream>>>(L3, Bb, B,32,16,48,48,2,2,2); }
  // stage 4: 32->64 @ 8x24x24 -> L4; pool(1,2,2) -> Cb   [COG=4]
  k_conv1_t<4><<<convgrid(8*24*24,64,4),TPB,0,stream>>>(Bb, w1[4], A, 32,64,8,24,24);
  k_conv2res_t<4><<<convgrid(8*24*24,64,4),TPB,0,stream>>>(A, Bb, w2[4], wsk[4], L4, 64,64,32,8,24,24);
  { ll np=(ll)B*64*8*12*12;
    k_maxpool<<<gridFor(np),TPB,0,stream>>>(L4, Cb, B,64,8,24,24,1,2,2); }
  // stage 5: 64->128 @ 8x12x12 -> L5; pool(1,2,2) -> P5   [COG=4]
  k_conv1_t<4><<<convgrid(8*12*12,128,4),TPB,0,stream>>>(Cb, w1[5], A, 64,128,8,12,12);
  k_conv2res_t<4><<<convgrid(8*12*12,128,4),TPB,0,stream>>>(A, Cb, w2[5], wsk[5], L5, 128,128,64,8,12,12);
  { ll np=(ll)B*128*8*6*6;
    k_maxpool<<<gridFor(np),TPB,0,stream>>>(L5, P5, B,128,8,12,12,1,2,2); }
  // stage 6: 128->128 @ 8x6x6, identity skip -> L6   [COG=2]
  k_conv1_t<2><<<convgrid(8*6*6,128,2),TPB,0,stream>>>(P5, w1[6], A, 128,128,8,6,6);
  k_conv2res_t<2><<<convgrid(8*6*6,128,2),TPB,0,stream>>>(A, P5, w2[6], nullptr, L6, 128,128,128,8,6,6);

  k_linear_red<<<dim3(B*64),TPB,0,stream>>>(P5, mu_w, mu_b, Z, 36864, 64);
  k_ld<<<gridFor((ll)B*88064),TPB,0,stream>>>(Z, ld_w, ld_b, DX, B, 88064, 64);

  // ============ Decoder (CSR cheb, fused hop kernels) ============
  auto build_csr = [&](const int* e, int N, int E){
    const int* row = e; const int* col = e + E;
    k_zero2<<<gridFor(N),TPB,0,stream>>>(DDEG, CNT, N);
    k_degcnt<<<gridFor(E),TPB,0,stream>>>(row, col, DDEG, CNT, E);
    k_scan<<<1,TPB,0,stream>>>(CNT, RP, CUR, N);
    k_fill<<<gridFor(E),TPB,0,stream>>>(row, col, DDEG, CUR, SRC, CW, E);
  };

  const int G = 4;
  auto cheb = [&](float* xin, float* t1, float* t2, float* xout,
                  const int* e, int N, int E, const float* Wg, int Ci, int Co, bool build){
    if(build) build_csr(e, N, E);
    ll BN = (ll)B*N;
    unsigned nb = (unsigned)((BN + G - 1)/G);
    size_t shm = (size_t)G*Ci*sizeof(float);
    k_cheb_hop<G><<<nb,TPB,shm,stream>>>(xin, nullptr, RP, SRC, CW, Wg, nullptr, xout, B,N,Ci,Co, 0);
    k_cheb_hop<G><<<nb,TPB,shm,stream>>>(xin, nullptr, RP, SRC, CW, Wg+(ll)Ci*Co, t1, xout, B,N,Ci,Co, 1);
    float *b0=xin, *b1=t1, *b2=t2;
    for(int k=2;k<6;++k){
      k_cheb_hop<G><<<nb,TPB,shm,stream>>>(b1, b0, RP, SRC, CW, Wg+(ll)k*Ci*Co, b2, xout, B,N,Ci,Co, 2);
      float* tmp=b0; b0=b1; b1=b2; b2=tmp;
    }
  };

  auto igsc = [&](float* x, float* cat, const float* ig, const float* feat,
                  int N, int Cx, int Cf, int D,int Hh,int Ww, float* ds){
    int Ctot = Cx + Cf + 3;
    ll BN = (ll)B*N;
    k_copycols<<<gridFor(BN*Cx),TPB,0,stream>>>(x, cat, BN, Cx, Ctot);
    k_pos<<<gridFor(BN),TPB,0,stream>>>(x, ig, cat, ds, BN, Cx, Ctot, Cx+Cf);
    k_gsample<<<gridFor(BN*(ll)Cf),TPB,0,stream>>>(feat, cat, B,N,Cf,D,Hh,Ww,Ctot,Cx,Cx+Cf);
  };

  float* out_x  = out;
  float* out_d4 = out + 132000;
  float* out_d3 = out + 198000;
  float* out_d2 = out + 231000;
  float* out_d1 = out + 247500;

  cheb(DX, DT1, DT2, DO_, edge[4], 688, 4128, gcw[0], 128, 64, true);
  k_inorm<<<gridFor((ll)B*688),TPB,0,stream>>>(DO_, gcb[0], (ll)B*688, 64);
  igsc(DO_, DCAT, igw[0], L6, 688, 64, 128, 8,6,6, out_d1);
  k_unpool<<<gridFor((ll)B*1375*195),TPB,0,stream>>>(DCAT, upidx[3], upw[3], DX, B, 688, 1375, 195);

  cheb(DX, DT1, DT2, DO_, edge[3], 1375, 8250, gcw[1], 195, 64, true);
  k_inorm<<<gridFor((ll)B*1375),TPB,0,stream>>>(DO_, gcb[1], (ll)B*1375, 64);
  igsc(DO_, DCAT, igw[1], L5, 1375, 64, 128, 8,12,12, out_d2);
  k_unpool<<<gridFor((ll)B*2750*195),TPB,0,stream>>>(DCAT, upidx[2], upw[2], DX, B, 1375, 2750, 195);

  cheb(DX, DT1, DT2, DO_, edge[2], 2750, 16500, gcw[2], 195, 32, true);
  k_inorm<<<gridFor((ll)B*2750),TPB,0,stream>>>(DO_, gcb[2], (ll)B*2750, 32);
  igsc(DO_, DCAT, igw[2], L4, 2750, 32, 64, 8,24,24, out_d3);
  k_unpool<<<gridFor((ll)B*5500*99),TPB,0,stream>>>(DCAT, upidx[1], upw[1], DX, B, 2750, 5500, 99);

  cheb(DX, DT1, DT2, DO_, edge[1], 5500, 33000, gcw[3], 99, 32, true);
  k_inorm<<<gridFor((ll)B*5500),TPB,0,stream>>>(DO_, gcb[3], (ll)B*5500, 32);
  igsc(DO_, DCAT, igw[3], L3, 5500, 32, 32, 16,48,48, out_d4);
  k_unpool<<<gridFor((ll)B*11000*67),TPB,0,stream>>>(DCAT, upidx[0], upw[0], DX, B, 5500, 11000, 67);

  cheb(DX, DT1, DT2, DO_, edge[0], 11000, 66000, gcw[4], 67, 32, true);
  k_inorm<<<gridFor((ll)B*11000),TPB,0,stream>>>(DO_, gcb[4], (ll)B*11000, 32);

  cheb(DO_, DT1, DT2, DCAT, edge[0], 11000, 66000, gcout_w, 32, 3, false);
  k_copy<<<gridFor(132000LL),TPB,0,stream>>>(DCAT, out_x, 132000LL);
}

// Round 13
// 3793.171 us; speedup vs baseline: 1.0235x; 1.0235x over previous
//
#include <hip/hip_runtime.h>

typedef long long ll;

#define TPB 256

static inline dim3 gridFor(ll n){ return dim3((unsigned)((n + TPB - 1) / TPB)); }

// ============ register-blocked conv kernels (small-spatial stages) ============
template<int COG>
__global__ void k_conv1_t(const float* __restrict__ x, const float* __restrict__ w,
                          float* __restrict__ out, int Ci,int Co,int D,int H,int W)
{
  int HW = H*W, DHW = D*HW;
  int sp = blockIdx.x*blockDim.x + threadIdx.x;
  if(sp>=DHW) return;
  int cg = blockIdx.y, b = blockIdx.z;
  int wv = sp % W, hv = (sp/W) % H, dv = sp / HW;
  ll plane = (ll)DHW;
  const float* xb = x + ((ll)b*Ci)*plane;
  const float* wb = w + ((ll)cg*COG)*Ci*27;
  float acc[COG];
#pragma unroll
  for(int u=0;u<COG;++u) acc[u]=0.f;
  float vd[3],vh[3],vw[3]; int cd[3],ch[3],cw[3];
#pragma unroll
  for(int k=0;k<3;++k){
    int dd=dv+k-1; vd[k]=((unsigned)dd<(unsigned)D)?1.f:0.f; cd[k]=min(max(dd,0),D-1);
    int hh=hv+k-1; vh[k]=((unsigned)hh<(unsigned)H)?1.f:0.f; ch[k]=min(max(hh,0),H-1);
    int ww=wv+k-1; vw[k]=((unsigned)ww<(unsigned)W)?1.f:0.f; cw[k]=min(max(ww,0),W-1);
  }
  for(int ci=0;ci<Ci;++ci){
    const float* xc = xb + (ll)ci*plane;
    float xv[27];
#pragma unroll
    for(int kd=0;kd<3;++kd)
#pragma unroll
      for(int kh=0;kh<3;++kh){
        const float* rowp = xc + ((ll)cd[kd]*H + ch[kh])*W;
        float vdh = vd[kd]*vh[kh];
#pragma unroll
        for(int kw=0;kw<3;++kw)
          xv[(kd*3+kh)*3+kw] = rowp[cw[kw]]*(vdh*vw[kw]);
      }
    const float* wc = wb + ci*27;
#pragma unroll
    for(int u=0;u<COG;++u){
      const float* wu = wc + (ll)u*Ci*27;
      float a = acc[u];
#pragma unroll
      for(int kk=0;kk<27;++kk) a += xv[kk]*wu[kk];
      acc[u]=a;
    }
  }
#pragma unroll
  for(int u=0;u<COG;++u)
    out[((ll)b*Co + cg*COG+u)*plane + sp] = fmaxf(acc[u],0.f);
}

template<int COG>
__global__ void k_conv2res_t(const float* __restrict__ cin, const float* __restrict__ xin,
                             const float* __restrict__ w2, const float* __restrict__ wsk,
                             float* __restrict__ out, int Cm,int Co,int Cs,int D,int H,int W)
{
  int HW = H*W, DHW = D*HW;
  int sp = blockIdx.x*blockDim.x + threadIdx.x;
  if(sp>=DHW) return;
  int cg = blockIdx.y, b = blockIdx.z;
  int wv = sp % W, hv = (sp/W) % H, dv = sp / HW;
  ll plane = (ll)DHW;
  float acc[COG];
  if(wsk){
    const float* xs = xin + ((ll)b*Cs)*plane + sp;
    const float* wr = wsk + (ll)cg*COG*Cs;
#pragma unroll
    for(int u=0;u<COG;++u) acc[u]=0.f;
    for(int cs=0;cs<Cs;++cs){
      float xv = xs[(ll)cs*plane];
#pragma unroll
      for(int u=0;u<COG;++u) acc[u] += xv*wr[(ll)u*Cs+cs];
    }
  } else {
#pragma unroll
    for(int u=0;u<COG;++u) acc[u] = xin[((ll)b*Co + cg*COG+u)*plane + sp];
  }
  float vd[3],vh[3],vw[3]; int cd[3],ch[3],cw[3];
#pragma unroll
  for(int k=0;k<3;++k){
    int dd=dv+k-1; vd[k]=((unsigned)dd<(unsigned)D)?1.f:0.f; cd[k]=min(max(dd,0),D-1);
    int hh=hv+k-1; vh[k]=((unsigned)hh<(unsigned)H)?1.f:0.f; ch[k]=min(max(hh,0),H-1);
    int ww=wv+k-1; vw[k]=((unsigned)ww<(unsigned)W)?1.f:0.f; cw[k]=min(max(ww,0),W-1);
  }
  const float* cb = cin + ((ll)b*Cm)*plane;
  const float* wb = w2 + ((ll)cg*COG)*Cm*27;
  for(int ci=0;ci<Cm;++ci){
    const float* xc = cb + (ll)ci*plane;
    float xv[27];
#pragma unroll
    for(int kd=0;kd<3;++kd)
#pragma unroll
      for(int kh=0;kh<3;++kh){
        const float* rowp = xc + ((ll)cd[kd]*H + ch[kh])*W;
        float vdh = vd[kd]*vh[kh];
#pragma unroll
        for(int kw=0;kw<3;++kw)
          xv[(kd*3+kh)*3+kw] = rowp[cw[kw]]*(vdh*vw[kw]);
      }
    const float* wc = wb + ci*27;
#pragma unroll
    for(int u=0;u<COG;++u){
      const float* wu = wc + (ll)u*Cm*27;
      float a = acc[u];
#pragma unroll
      for(int kk=0;kk<27;++kk) a += xv[kk]*wu[kk];
      acc[u]=a;
    }
  }
#pragma unroll
  for(int u=0;u<COG;++u)
    out[((ll)b*Co + cg*COG+u)*plane + sp] = fmaxf(acc[u],0.f);
}

// ============ LDS-tiled conv kernels (large-spatial, H,W%16==0) ============
#define C1_RS 24
template<int COG>
__global__ void k_conv1_lds(const float* __restrict__ x, const float* __restrict__ w,
                            float* __restrict__ out, int Ci,int Co,int D,int H,int W)
{
  const int TO = 16;
  int tilesX = W/TO, tilesY = H/TO;
  int tx = threadIdx.x & 15, ty = threadIdx.x >> 4;
  int bx = blockIdx.x;
  int tX = bx % tilesX; int tmp = bx / tilesX;
  int tY = tmp % tilesY; int dv = tmp / tilesY;
  int cg = blockIdx.y, b = blockIdx.z;
  int oh = tY*TO + ty, ow = tX*TO + tx;
  ll plane = (ll)D*H*W;
  int hbase = tY*TO - 1, wbase = tX*TO - 1;
  __shared__ float lds[3*18*C1_RS];
  float acc[COG];
#pragma unroll
  for(int u=0;u<COG;++u) acc[u]=0.f;
  const float* xb = x + ((ll)b*Ci)*plane;
  const float* wb = w + ((ll)cg*COG)*Ci*27;
  for(int ci=0;ci<Ci;++ci){
    const float* xc = xb + (ll)ci*plane;
    for(int idx=threadIdx.x; idx<3*18*18; idx+=TPB){
      int kd = idx / 324; int rem = idx - kd*324;
      int r = rem / 18, c2 = rem - r*18;
      int dd = dv + kd - 1, hh = hbase + r, ww = wbase + c2;
      float v = 0.f;
      if((unsigned)dd<(unsigned)D && (unsigned)hh<(unsigned)H && (unsigned)ww<(unsigned)W)
        v = xc[((ll)dd*H + hh)*W + ww];
      lds[(kd*18 + r)*C1_RS + c2] = v;
    }
    __syncthreads();
    float xv[27];
#pragma unroll
    for(int kd=0;kd<3;++kd)
#pragma unroll
      for(int kh=0;kh<3;++kh)
#pragma unroll
        for(int kw=0;kw<3;++kw)
          xv[(kd*3+kh)*3+kw] = lds[(kd*18 + (ty+kh))*C1_RS + (tx+kw)];
    const float* wc = wb + ci*27;
#pragma unroll
    for(int u=0;u<COG;++u){
      const float* wu = wc + (ll)u*Ci*27;
      float a = acc[u];
#pragma unroll
      for(int kk=0;kk<27;++kk) a += xv[kk]*wu[kk];
      acc[u]=a;
    }
    __syncthreads();
  }
  ll sp = ((ll)dv*H + oh)*W + ow;
#pragma unroll
  for(int u=0;u<COG;++u)
    out[((ll)b*Co + cg*COG+u)*plane + sp] = fmaxf(acc[u],0.f);
}

template<int COG>
__global__ void k_conv2res_lds(const float* __restrict__ cin, const float* __restrict__ xin,
                               const float* __restrict__ w2, const float* __restrict__ wsk,
                               float* __restrict__ out, int Cm,int Co,int Cs,int D,int H,int W)
{
  const int TO = 16;
  int tilesX = W/TO, tilesY = H/TO;
  int tx = threadIdx.x & 15, ty = threadIdx.x >> 4;
  int bx = blockIdx.x;
  int tX = bx % tilesX; int tmp = bx / tilesX;
  int tY = tmp % tilesY; int dv = tmp / tilesY;
  int cg = blockIdx.y, b = blockIdx.z;
  int oh = tY*TO + ty, ow = tX*TO + tx;
  ll plane = (ll)D*H*W;
  int hbase = tY*TO - 1, wbase = tX*TO - 1;
  __shared__ float lds[3*18*C1_RS];
  ll sp = ((ll)dv*H + oh)*W + ow;
  float acc[COG];
  {
    const float* xs = xin + ((ll)b*Cs)*plane + sp;
    const float* wr = wsk + (ll)cg*COG*Cs;
#pragma unroll
    for(int u=0;u<COG;++u) acc[u]=0.f;
    for(int cs=0;cs<Cs;++cs){
      float xv = xs[(ll)cs*plane];
#pragma unroll
      for(int u=0;u<COG;++u) acc[u] += xv*wr[(ll)u*Cs+cs];
    }
  }
  const float* cb = cin + ((ll)b*Cm)*plane;
  const float* wb = w2 + ((ll)cg*COG)*Cm*27;
  for(int ci=0;ci<Cm;++ci){
    const float* xc = cb + (ll)ci*plane;
    for(int idx=threadIdx.x; idx<3*18*18; idx+=TPB){
      int kd = idx / 324; int rem = idx - kd*324;
      int r = rem / 18, c2 = rem - r*18;
      int dd = dv + kd - 1, hh = hbase + r, ww = wbase + c2;
      float v = 0.f;
      if((unsigned)dd<(unsigned)D && (unsigned)hh<(unsigned)H && (unsigned)ww<(unsigned)W)
        v = xc[((ll)dd*H + hh)*W + ww];
      lds[(kd*18 + r)*C1_RS + c2] = v;
    }
    __syncthreads();
    float xv[27];
#pragma unroll
    for(int kd=0;kd<3;++kd)
#pragma unroll
      for(int kh=0;kh<3;++kh)
#pragma unroll
        for(int kw=0;kw<3;++kw)
          xv[(kd*3+kh)*3+kw] = lds[(kd*18 + (ty+kh))*C1_RS + (tx+kw)];
    const float* wc = wb + ci*27;
#pragma unroll
    for(int u=0;u<COG;++u){
      const float* wu = wc + (ll)u*Cm*27;
      float a = acc[u];
#pragma unroll
      for(int kk=0;kk<27;++kk) a += xv[kk]*wu[kk];
      acc[u]=a;
    }
    __syncthreads();
  }
#pragma unroll
  for(int u=0;u<COG;++u)
    out[((ll)b*Co + cg*COG+u)*plane + sp] = fmaxf(acc[u],0.f);
}

// ============ LDS-tiled conv2 + skip + relu + maxpool(1,2,2) — round-11 layout ============
template<int COG>
__global__ void k_conv2respool_lds(const float* __restrict__ cin, const float* __restrict__ xin,
                                   const float* __restrict__ w2, const float* __restrict__ wsk,
                                   float* __restrict__ out, int Cm,int Co,int Cs,int D,int H,int W)
{
  const int TO = 16;
  int Ho=H/2, Wo=W/2;
  int tilesX = Wo/TO, tilesY = Ho/TO;
  int tx = threadIdx.x & 15, ty = threadIdx.x >> 4;
  int bx = blockIdx.x;
  int tX = bx % tilesX; int tmp = bx / tilesX;
  int tY = tmp % tilesY; int dv = tmp / tilesY;
  int cg = blockIdx.y, b = blockIdx.z;
  int oh = tY*TO + ty, ow = tX*TO + tx;
  ll plane = (ll)D*H*W;
  int hbase = tY*2*TO - 1, wbase = tX*2*TO - 1;
  __shared__ float lds[3*34*34];

  float acc[COG][4];
#pragma unroll
  for(int u=0;u<COG;++u){
#pragma unroll
    for(int p=0;p<4;++p) acc[u][p]=0.f;
  }
  {
    int hv=2*oh, wv=2*ow;
    ll p00 = ((ll)dv*H + hv)*W + wv;
    const float* xb = xin + ((ll)b*Cs)*plane;
    const float* wr = wsk + (ll)cg*COG*Cs;
    for(int cs=0;cs<Cs;++cs){
      const float* xc = xb + (ll)cs*plane;
      float s00=xc[p00], s01=xc[p00+1], s10=xc[p00+W], s11=xc[p00+W+1];
#pragma unroll
      for(int u=0;u<COG;++u){
        float wv_ = wr[(ll)u*Cs+cs];
        acc[u][0]+=s00*wv_; acc[u][1]+=s01*wv_; acc[u][2]+=s10*wv_; acc[u][3]+=s11*wv_;
      }
    }
  }
  const float* cb = cin + ((ll)b*Cm)*plane;
  const float* wb = w2 + ((ll)cg*COG)*Cm*27;
  for(int ci=0;ci<Cm;++ci){
    const float* xc = cb + (ll)ci*plane;
    for(int idx=threadIdx.x; idx<3*34*34; idx+=TPB){
      int kd = idx / 1156; int rem = idx - kd*1156;
      int r = rem / 34, c2 = rem - r*34;
      int dd = dv + kd - 1, hh = hbase + r, ww = wbase + c2;
      float v = 0.f;
      if((unsigned)dd<(unsigned)D && (unsigned)hh<(unsigned)H && (unsigned)ww<(unsigned)W)
        v = xc[((ll)dd*H + hh)*W + ww];
      lds[idx] = v;
    }
    __syncthreads();
    float xv[3][4][4];
#pragma unroll
    for(int kd=0;kd<3;++kd)
#pragma unroll
      for(int r=0;r<4;++r)
#pragma unroll
        for(int j=0;j<4;++j)
          xv[kd][r][j] = lds[(kd*34 + (2*ty+r))*34 + (2*tx+j)];
    const float* wc = wb + ci*27;
#pragma unroll
    for(int u=0;u<COG;++u){
      const float* wu = wc + (ll)u*Cm*27;
#pragma unroll
      for(int py=0;py<2;++py)
#pragma unroll
        for(int px=0;px<2;++px){
          float a = acc[u][py*2+px];
#pragma unroll
          for(int kd=0;kd<3;++kd)
#pragma unroll
            for(int kh=0;kh<3;++kh)
#pragma unroll
              for(int kw=0;kw<3;++kw)
                a += xv[kd][py+kh][px+kw]*wu[(kd*3+kh)*3+kw];
          acc[u][py*2+px]=a;
        }
    }
    __syncthreads();
  }
#pragma unroll
  for(int u=0;u<COG;++u){
    float mm = fmaxf(fmaxf(acc[u][0],acc[u][1]),fmaxf(acc[u][2],acc[u][3]));
    out[(((ll)b*Co + cg*COG+u)*D + dv)*(Ho*Wo) + oh*Wo + ow] = fmaxf(mm,0.f);
  }
}

// ---------------- maxpool3d ----------------
__global__ void k_maxpool(const float* __restrict__ x, float* __restrict__ out,
                          int B,int C,int D,int H,int W,int pd,int ph,int pw)
{
  int Do = D/pd, Ho = H/ph, Wo = W/pw;
  ll total = (ll)B*C*Do*Ho*Wo;
  ll i = (ll)blockIdx.x*blockDim.x + threadIdx.x;
  if(i>=total) return;
  int w0 = (int)(i % Wo); ll t = i / Wo;
  int h0 = (int)(t % Ho); t /= Ho;
  int d0 = (int)(t % Do); t /= Do;
  int c  = (int)(t % C);  int b = (int)(t / C);
  const float* xb = x + ((ll)b*C + c)*D*H*W;
  float m = -3.4e38f;
  for(int dd=0; dd<pd; ++dd)
    for(int hh=0; hh<ph; ++hh)
      for(int ww=0; ww<pw; ++ww){
        float v = xb[(((ll)(d0*pd+dd))*H + (h0*ph+hh))*W + (w0*pw+ww)];
        m = fmaxf(m, v);
      }
  out[i] = m;
}

// ---------------- mu linear ----------------
__global__ void k_linear_red(const float* __restrict__ x, const float* __restrict__ w,
                             const float* __restrict__ bias, float* __restrict__ out,
                             int In, int Out)
{
  int o = blockIdx.x % Out;
  int b = blockIdx.x / Out;
  const float* xr = x + (ll)b*In;
  const float* wr = w + (ll)o*In;
  float s = 0.f;
  for(int i = threadIdx.x; i < In; i += blockDim.x) s += xr[i]*wr[i];
  __shared__ float red[TPB];
  red[threadIdx.x] = s; __syncthreads();
  for(int off = TPB/2; off > 0; off >>= 1){
    if(threadIdx.x < off) red[threadIdx.x] += red[threadIdx.x + off];
    __syncthreads();
  }
  if(threadIdx.x == 0) out[blockIdx.x] = red[0] + bias[o];
}

// ---------------- latent->decoder linear + relu ----------------
__global__ void k_ld(const float* __restrict__ z, const float* __restrict__ w,
                     const float* __restrict__ bias, float* __restrict__ out,
                     int B,int Out,int L)
{
  ll i = (ll)blockIdx.x*blockDim.x + threadIdx.x;
  if(i >= (ll)B*Out) return;
  int o = (int)(i % Out); int b = (int)(i / Out);
  const float* zr = z + (ll)b*L;
  const float* wr = w + (ll)o*L;
  float s = bias[o];
  for(int l=0; l<L; ++l) s += zr[l]*wr[l];
  out[i] = fmaxf(s, 0.f);
}

// ================= batched CSR build (all 5 graphs in 4 launches) =================
struct CsrOffs { int N[5]; int nOff[5]; int rpOff[5]; int eOff[5]; };

__global__ void k_csr_zero(float* __restrict__ deg, int* __restrict__ cnt, int tot){
  int i = blockIdx.x*blockDim.x + threadIdx.x;
  if(i<tot){ deg[i]=0.f; cnt[i]=0; }
}
__global__ void k_csr_degcnt(const int* e0,const int* e1,const int* e2,const int* e3,const int* e4,
                             CsrOffs o, float* __restrict__ deg, int* __restrict__ cnt){
  int g = blockIdx.y;
  int E = 6*o.N[g];
  int e = blockIdx.x*blockDim.x + threadIdx.x;
  if(e>=E) return;
  const int* eg = (g==0)?e0:(g==1)?e1:(g==2)?e2:(g==3)?e3:e4;
  int nb = o.nOff[g];
  atomicAdd(&deg[nb+eg[e]], 1.f);
  atomicAdd(&cnt[nb+eg[E+e]], 1);
}
__global__ void k_csr_scan(CsrOffs o, const int* __restrict__ cnt,
                           int* __restrict__ rp, int* __restrict__ cur){
  int g = blockIdx.x;
  int N = o.N[g]; int nb = o.nOff[g]; int rb = o.rpOff[g];
  __shared__ int ps[TPB];
  int t = threadIdx.x;
  int chunk = (N + TPB - 1)/TPB;
  int s0 = t*chunk, s1 = min(s0+chunk, N);
  int sum = 0;
  for(int i=s0;i<s1;++i) sum += cnt[nb+i];
  ps[t] = sum; __syncthreads();
  for(int off=1; off<TPB; off<<=1){
    int v = (t>=off)? ps[t-off] : 0; __syncthreads();
    ps[t] += v; __syncthreads();
  }
  int base = (t==0)? 0 : ps[t-1];
  for(int i=s0;i<s1;++i){ rp[rb+i]=base; cur[nb+i]=base; base += cnt[nb+i]; }
  if(s1==N) rp[rb+N]=base;
}
__global__ void k_csr_fill(const int* e0,const int* e1,const int* e2,const int* e3,const int* e4,
                           CsrOffs o, const float* __restrict__ deg, int* __restrict__ cur,
                           int* __restrict__ src, float* __restrict__ cw){
  int g = blockIdx.y;
  int E = 6*o.N[g];
  int e = blockIdx.x*blockDim.x + threadIdx.x;
  if(e>=E) return;
  const int* eg = (g==0)?e0:(g==1)?e1:(g==2)?e2:(g==3)?e3:e4;
  int nb = o.nOff[g], eb = o.eOff[g];
  int r = eg[e], c = eg[E+e];
  float dr = deg[nb+r], dc = deg[nb+c];
  float ir = dr > 0.f ? rsqrtf(dr) : 0.f;
  float ic = dc > 0.f ? rsqrtf(dc) : 0.f;
  int pos = atomicAdd(&cur[nb+c], 1);
  src[eb+pos] = r;
  cw[eb+pos] = -(ir*ic);
}

// ================= fused Chebyshev hop =================
template<int G>
__global__ void k_cheb_hop(const float* __restrict__ v, const float* __restrict__ t0,
                           const int* __restrict__ rowptr, const int* __restrict__ src,
                           const float* __restrict__ cw, const float* __restrict__ Wk,
                           float* __restrict__ t2, float* __restrict__ xout,
                           int B,int N,int Ci,int Co,int mode)
{
  extern __shared__ float lds[]; // G*Ci
  ll g0 = (ll)blockIdx.x*G;
  ll BN = (ll)B*N;
  int tot = G*Ci;
  for(int idx=threadIdx.x; idx<tot; idx+=blockDim.x){
    int g = idx / Ci, c = idx - g*Ci;
    ll bj = g0 + g;
    float s = 0.f;
    if(bj < BN){
      if(mode==0){
        s = v[bj*(ll)Ci + c];
      } else {
        int b = (int)(bj / N), j = (int)(bj - (ll)b*N);
        int e0 = rowptr[j], e1 = rowptr[j+1];
        const float* vb = v + (ll)b*N*Ci;
        for(int e=e0;e<e1;++e) s += vb[(ll)src[e]*Ci + c]*cw[e];
        if(mode==2) s = 2.f*s - t0[bj*(ll)Ci + c];
        t2[bj*(ll)Ci + c] = s;
      }
    }
    lds[idx] = s;
  }
  __syncthreads();
  int totB = G*Co;
  for(int idx=threadIdx.x; idx<totB; idx+=blockDim.x){
    int g = idx / Co, co = idx - g*Co;
    ll bj = g0 + g;
    if(bj >= BN) continue;
    const float* tr = lds + g*Ci;
    float s = 0.f;
    for(int c=0;c<Ci;++c) s += tr[c]*Wk[(ll)c*Co + co];
    if(mode==0) xout[bj*(ll)Co+co] = s;
    else xout[bj*(ll)Co+co] += s;
  }
}

__global__ void k_inorm(float* __restrict__ x, const float* __restrict__ bias, ll BN, int C)
{
  ll r = (ll)blockIdx.x*blockDim.x + threadIdx.x;
  if(r>=BN) return;
  float* xr = x + r*(ll)C;
  float mu = 0.f;
  for(int c=0;c<C;++c){ float v = xr[c] + bias[c]; xr[c]=v; mu += v; }
  mu /= (float)C;
  float var = 0.f;
  for(int c=0;c<C;++c){ float d = xr[c]-mu; var += d*d; }
  var /= (float)C;
  float inv = rsqrtf(var + 1e-5f);
  for(int c=0;c<C;++c) xr[c] = fmaxf((xr[c]-mu)*inv, 0.f);
}

// ---------------- IGSC: fused copycols + pos ----------------
__global__ void k_igsc_pre(const float* __restrict__ x, const float* __restrict__ igw,
                           float* __restrict__ cat, float* __restrict__ ds,
                           ll BN, int Cx, int Ctot, int posoff)
{
  ll i = (ll)blockIdx.x*blockDim.x + threadIdx.x;
  ll tot = BN*(ll)(Cx+3);
  if(i>=tot) return;
  int c = (int)(i % (Cx+3)); ll r = i / (Cx+3);
  if(c < Cx){
    cat[r*(ll)Ctot + c] = x[r*(ll)Cx + c];
  } else {
    int p = c - Cx;
    const float* xr = x + r*(ll)Cx;
    float s = 0.f;
    for(int cc=0;cc<Cx;++cc) s += xr[cc]*igw[cc*3+p];
    cat[r*(ll)Ctot + posoff + p] = s;
    ds[r*3+p] = s;
  }
}
__global__ void k_gsample(const float* __restrict__ feat, float* __restrict__ cat,
                          int B,int N,int Cf,int D,int H,int W,int Ctot,int xoff,int posoff)
{
  ll i = (ll)blockIdx.x*blockDim.x + threadIdx.x;
  ll total = (ll)B*N*Cf;
  if(i>=total) return;
  int c = (int)(i % Cf); ll t = i / Cf;
  int n = (int)(t % N); int b = (int)(t / N);
  float* rowp = cat + ((ll)b*N + n)*Ctot;
  float px = rowp[posoff+0], py = rowp[posoff+1], pz = rowp[posoff+2];
  float gx = (2.f*px - 1.f + 1.f)*0.5f*(W-1);
  float gy = (2.f*py - 1.f + 1.f)*0.5f*(H-1);
  float gz = (2.f*pz - 1.f + 1.f)*0.5f*(D-1);
  float x0 = floorf(gx), y0 = floorf(gy), z0 = floorf(gz);
  const float* fb = feat + ((ll)b*Cf + c)*D*H*W;
  float acc = 0.f;
  for(int dz=0; dz<2; ++dz)
    for(int dy=0; dy<2; ++dy)
      for(int dx=0; dx<2; ++dx){
        float xi = x0+dx, yi = y0+dy, zi = z0+dz;
        float wgt = (1.f-fabsf(gx-xi))*(1.f-fabsf(gy-yi))*(1.f-fabsf(gz-zi));
        bool valid = (xi>=0.f)&&(xi<=(float)(W-1))&&(yi>=0.f)&&(yi<=(float)(H-1))&&(zi>=0.f)&&(zi<=(float)(D-1));
        int xc = min(max((int)xi,0),W-1);
        int yc = min(max((int)yi,0),H-1);
        int zc = min(max((int)zi,0),D-1);
        if(valid) acc += fb[((ll)zc*H + yc)*W + xc]*wgt;
      }
  rowp[xoff + c] = acc;
}

// ---------------- unpool ----------------
__global__ void k_unpool(const float* __restrict__ xin, const int* __restrict__ idx,
                         const float* __restrict__ w, float* __restrict__ out,
                         int B,int Ni,int No,int C)
{
  ll i = (ll)blockIdx.x*blockDim.x + threadIdx.x;
  ll total = (ll)B*No*C;
  if(i>=total) return;
  int c = (int)(i % C); ll t = i / C;
  int no = (int)(t % No); int b = (int)(t / No);
  float s = 0.f;
  for(int k=0;k<3;++k){
    s += xin[((ll)b*Ni + idx[no*3+k])*C + c]*w[no*3+k];
  }
  out[i] = s;
}

// ================= workspace layout (BYTE offsets) =================
static const ll BO_A   = 0;
static const ll BO_B   = 75497472;
static const ll BO_C   = 94371840;
static const ll BO_L3  = 103809024;
static const ll BO_L4  = 122683392;
static const ll BO_L5  = 127401984;
static const ll BO_L6  = 129761280;
static const ll BO_P5  = 130940928;
static const ll BO_Z   = 132120576;
// decoder regions inside arena A
static const ll BO_DX   = 0;
static const ll BO_DT1  = 11792000;
static const ll BO_DT2  = 23584000;
static const ll BO_DO   = 35376000;
static const ll BO_DCAT = 41008000;
// batched CSR arena (21313 nodes, 127878 edges total)
static const ll BO_DDEG = 46904000;    // float[21313]
static const ll BO_CNT  = 46989504;    // int[21313]
static const ll BO_RP   = 47075008;    // int[21318]
static const ll BO_CUR  = 47160512;    // int[21313]
static const ll BO_SRC  = 47246016;    // int[127878]
static const ll BO_CW   = 47757632;    // float[127878] -> end 48,269,144

extern "C" void kernel_launch(void* const* d_in, const int* in_sizes, int n_in,
                              void* d_out, int out_size, void* d_ws, size_t ws_size,
                              hipStream_t stream)
{
  (void)in_sizes; (void)n_in; (void)out_size; (void)ws_size;
  const int B = 4;
  const float* sax = (const float*)d_in[0];
  const float *w1[7], *w2[7], *wsk[7];
  for(int i=1;i<=5;++i){
    w1[i]  = (const float*)d_in[1 + (i-1)*3];
    w2[i]  = (const float*)d_in[2 + (i-1)*3];
    wsk[i] = (const float*)d_in[3 + (i-1)*3];
  }
  w1[6] = (const float*)d_in[16]; w2[6] = (const float*)d_in[17]; wsk[6] = nullptr;
  const float* mu_w = (const float*)d_in[18];
  const float* mu_b = (const float*)d_in[19];
  const float* ld_w = (const float*)d_in[22];
  const float* ld_b = (const float*)d_in[23];
  const float *gcw[5], *gcb[5];
  for(int i=0;i<5;++i){ gcw[i] = (const float*)d_in[24+2*i]; gcb[i] = (const float*)d_in[25+2*i]; }
  const float* gcout_w = (const float*)d_in[34];
  const float* igw[4];
  for(int i=0;i<4;++i) igw[i] = (const float*)d_in[35+i];
  const int* edge[5];
  for(int i=0;i<5;++i) edge[i] = (const int*)d_in[39+i];
  const int* upidx[4]; const float* upw[4];
  for(int i=0;i<4;++i){ upidx[i] = (const int*)d_in[44+2*i]; upw[i] = (const float*)d_in[45+2*i]; }
  float* out = (float*)d_out;
  char* base = (char*)d_ws;

  float* A  = (float*)(base + BO_A);
  float* Bb = (float*)(base + BO_B);
  float* Cb = (float*)(base + BO_C);
  float* L3 = (float*)(base + BO_L3);
  float* L4 = (float*)(base + BO_L4);
  float* L5 = (float*)(base + BO_L5);
  float* L6 = (float*)(base + BO_L6);
  float* P5 = (float*)(base + BO_P5);
  float* Z  = (float*)(base + BO_Z);
  float* DX  = (float*)(base + BO_DX);
  float* DT1 = (float*)(base + BO_DT1);
  float* DT2 = (float*)(base + BO_DT2);
  float* DO_ = (float*)(base + BO_DO);
  float* DCAT= (float*)(base + BO_DCAT);
  float* DDEG= (float*)(base + BO_DDEG);
  int*   CNT = (int*)(base + BO_CNT);
  int*   RP  = (int*)(base + BO_RP);
  int*   CUR = (int*)(base + BO_CUR);
  int*   SRC = (int*)(base + BO_SRC);
  float* CW  = (float*)(base + BO_CW);

  // ============ Encoder ============
  auto convgrid = [&](int DHW, int Co, int COG){ return dim3((unsigned)((DHW+TPB-1)/TPB), Co/COG, B); };
  auto tilegrid = [&](int D,int H,int W,int Co,int COG){
    return dim3((unsigned)((H/16)*(W/16)*D), Co/COG, B);
  };

  k_conv1_lds<8><<<tilegrid(16,192,192,8,8),TPB,0,stream>>>(sax, w1[1], A, 1,8,16,192,192);
  k_conv2respool_lds<8><<<tilegrid(16,96,96,8,8),TPB,0,stream>>>(A, sax, w2[1], wsk[1], Bb, 8,8,1,16,192,192);
  k_conv1_lds<16><<<tilegrid(16,96,96,16,16),TPB,0,stream>>>(Bb, w1[2], A, 8,16,16,96,96);
  k_conv2respool_lds<8><<<tilegrid(16,48,48,16,8),TPB,0,stream>>>(A, Bb, w2[2], wsk[2], Cb, 16,16,8,16,96,96);
  k_conv1_lds<16><<<tilegrid(16,48,48,32,16),TPB,0,stream>>>(Cb, w1[3], A, 16,32,16,48,48);
  k_conv2res_lds<16><<<tilegrid(16,48,48,32,16),TPB,0,stream>>>(A, Cb, w2[3], wsk[3], L3, 32,32,16,16,48,48);
  { ll np=(ll)B*32*8*24*24;
    k_maxpool<<<gridFor(np),TPB,0,stream>>>(L3, Bb, B,32,16,48,48,2,2,2); }
  k_conv1_t<4><<<convgrid(8*24*24,64,4),TPB,0,stream>>>(Bb, w1[4], A, 32,64,8,24,24);
  k_conv2res_t<4><<<convgrid(8*24*24,64,4),TPB,0,stream>>>(A, Bb, w2[4], wsk[4], L4, 64,64,32,8,24,24);
  { ll np=(ll)B*64*8*12*12;
    k_maxpool<<<gridFor(np),TPB,0,stream>>>(L4, Cb, B,64,8,24,24,1,2,2); }
  k_conv1_t<4><<<convgrid(8*12*12,128,4),TPB,0,stream>>>(Cb, w1[5], A, 64,128,8,12,12);
  k_conv2res_t<4><<<convgrid(8*12*12,128,4),TPB,0,stream>>>(A, Cb, w2[5], wsk[5], L5, 128,128,64,8,12,12);
  { ll np=(ll)B*128*8*6*6;
    k_maxpool<<<gridFor(np),TPB,0,stream>>>(L5, P5, B,128,8,12,12,1,2,2); }
  k_conv1_t<2><<<convgrid(8*6*6,128,2),TPB,0,stream>>>(P5, w1[6], A, 128,128,8,6,6);
  k_conv2res_t<2><<<convgrid(8*6*6,128,2),TPB,0,stream>>>(A, P5, w2[6], nullptr, L6, 128,128,128,8,6,6);

  k_linear_red<<<dim3(B*64),TPB,0,stream>>>(P5, mu_w, mu_b, Z, 36864, 64);
  k_ld<<<gridFor((ll)B*88064),TPB,0,stream>>>(Z, ld_w, ld_b, DX, B, 88064, 64);

  // ============ Batched CSR build (all 5 graphs, 4 launches) ============
  CsrOffs offs;
  { int N_[5]={11000,5500,2750,1375,688};
    int no=0, eo=0;
    for(int g=0; g<5; ++g){
      offs.N[g]=N_[g]; offs.nOff[g]=no; offs.rpOff[g]=no+g; offs.eOff[g]=eo;
      no += N_[g]; eo += 6*N_[g];
    } }
  const int TOTN = 21313, MAXE = 66000;
  k_csr_zero<<<gridFor(TOTN),TPB,0,stream>>>(DDEG, CNT, TOTN);
  { dim3 g((unsigned)((MAXE+TPB-1)/TPB), 5);
    k_csr_degcnt<<<g,TPB,0,stream>>>(edge[0],edge[1],edge[2],edge[3],edge[4], offs, DDEG, CNT);
    k_csr_scan<<<dim3(5),TPB,0,stream>>>(offs, CNT, RP, CUR);
    k_csr_fill<<<g,TPB,0,stream>>>(edge[0],edge[1],edge[2],edge[3],edge[4], offs, DDEG, CUR, SRC, CW); }

  // ============ Decoder ============
  const int G = 4;
  auto cheb = [&](float* xin, float* t1, float* t2, float* xout,
                  int gi, const float* Wg, int Ci, int Co){
    int N = offs.N[gi];
    const int* RPg = RP + offs.rpOff[gi];
    const int* SRCg = SRC + offs.eOff[gi];
    const float* CWg = CW + offs.eOff[gi];
    ll BN = (ll)B*N;
    unsigned nb = (unsigned)((BN + G - 1)/G);
    size_t shm = (size_t)G*Ci*sizeof(float);
    k_cheb_hop<G><<<nb,TPB,shm,stream>>>(xin, nullptr, RPg, SRCg, CWg, Wg, nullptr, xout, B,N,Ci,Co, 0);
    k_cheb_hop<G><<<nb,TPB,shm,stream>>>(xin, nullptr, RPg, SRCg, CWg, Wg+(ll)Ci*Co, t1, xout, B,N,Ci,Co, 1);
    float *b0=xin, *b1=t1, *b2=t2;
    for(int k=2;k<6;++k){
      k_cheb_hop<G><<<nb,TPB,shm,stream>>>(b1, b0, RPg, SRCg, CWg, Wg+(ll)k*Ci*Co, b2, xout, B,N,Ci,Co, 2);
      float* tmp=b0; b0=b1; b1=b2; b2=tmp;
    }
  };

  auto igsc = [&](float* x, float* cat, const float* ig, const float* feat,
                  int N, int Cx, int Cf, int D,int Hh,int Ww, float* ds){
    int Ctot = Cx + Cf + 3;
    ll BN = (ll)B*N;
    k_igsc_pre<<<gridFor(BN*(ll)(Cx+3)),TPB,0,stream>>>(x, ig, cat, ds, BN, Cx, Ctot, Cx+Cf);
    k_gsample<<<gridFor(BN*(ll)Cf),TPB,0,stream>>>(feat, cat, B,N,Cf,D,Hh,Ww,Ctot,Cx,Cx+Cf);
  };

  float* out_x  = out;
  float* out_d4 = out + 132000;
  float* out_d3 = out + 198000;
  float* out_d2 = out + 231000;
  float* out_d1 = out + 247500;

  cheb(DX, DT1, DT2, DO_, 4, gcw[0], 128, 64);
  k_inorm<<<gridFor((ll)B*688),TPB,0,stream>>>(DO_, gcb[0], (ll)B*688, 64);
  igsc(DO_, DCAT, igw[0], L6, 688, 64, 128, 8,6,6, out_d1);
  k_unpool<<<gridFor((ll)B*1375*195),TPB,0,stream>>>(DCAT, upidx[3], upw[3], DX, B, 688, 1375, 195);

  cheb(DX, DT1, DT2, DO_, 3, gcw[1], 195, 64);
  k_inorm<<<gridFor((ll)B*1375),TPB,0,stream>>>(DO_, gcb[1], (ll)B*1375, 64);
  igsc(DO_, DCAT, igw[1], L5, 1375, 64, 128, 8,12,12, out_d2);
  k_unpool<<<gridFor((ll)B*2750*195),TPB,0,stream>>>(DCAT, upidx[2], upw[2], DX, B, 1375, 2750, 195);

  cheb(DX, DT1, DT2, DO_, 2, gcw[2], 195, 32);
  k_inorm<<<gridFor((ll)B*2750),TPB,0,stream>>>(DO_, gcb[2], (ll)B*2750, 32);
  igsc(DO_, DCAT, igw[2], L4, 2750, 32, 64, 8,24,24, out_d3);
  k_unpool<<<gridFor((ll)B*5500*99),TPB,0,stream>>>(DCAT, upidx[1], upw[1], DX, B, 2750, 5500, 99);

  cheb(DX, DT1, DT2, DO_, 1, gcw[3], 99, 32);
  k_inorm<<<gridFor((ll)B*5500),TPB,0,stream>>>(DO_, gcb[3], (ll)B*5500, 32);
  igsc(DO_, DCAT, igw[3], L3, 5500, 32, 32, 16,48,48, out_d4);
  k_unpool<<<gridFor((ll)B*11000*67),TPB,0,stream>>>(DCAT, upidx[0], upw[0], DX, B, 5500, 11000, 67);

  cheb(DX, DT1, DT2, DO_, 0, gcw[4], 67, 32);
  k_inorm<<<gridFor((ll)B*11000),TPB,0,stream>>>(DO_, gcb[4], (ll)B*11000, 32);

  // GCout: write directly into d_out (x output region)
  cheb(DO_, DT1, DT2, out_x, 0, gcout_w, 32, 3);
}